// Round 3
// baseline (433.169 us; speedup 1.0000x reference)
//
#include <hip/hip_runtime.h>
#include <stdint.h>

#define NTAG    10
#define SEQ     512
#define BATCH   8192
#define NEG_INF -10000.0f
#define BT10    (BATCH * NTAG)    // 81920: per-timestep dword stride in feats/bpw

// DPP row_ror:K within 16-lane rows (VALU-speed cross-lane, no LDS pipe).
template<int K>
__device__ __forceinline__ int ror16(int v) {
    return __builtin_amdgcn_mov_dpp(v, 0x120 + K, 0xF, 0xF, false);
}

// ---------------------------------------------------------------------------
// Forward Viterbi, DPP edition. 16 lanes per batch element (tags 0..15; tags
// 10..15 are padding whose transitions are NEG_INF so they never win the max:
// pad fv tracks global_max-10000, pad candidates sit ~20000 below real ones).
// 2048 waves -> 2 waves/SIMD. Per step: 15 independent row_ror's of fv + a
// running strict-> (max, argmax) chain. pid[k] = source-lane tag for rotation
// k, built with the SAME dpp op -> correct regardless of ROR direction.
// Exact fp32: cand = fv[p] + T[n][p]; fv' = max + feat — identical adds to ref.
// ---------------------------------------------------------------------------
__global__ __launch_bounds__(256) void crf_fwd(
    const float* __restrict__ feats, const float* __restrict__ trans,
    float* __restrict__ path_score, int* __restrict__ last_tag,
    uint32_t* __restrict__ bpw)
{
    const int tid  = threadIdx.x;
    const int lane = tid & 63;
    const int nx   = lane & 15;           // tag slot
    const int wave = tid >> 6;
    const int grp  = lane >> 4;           // batch subgroup within wave
    const int b    = blockIdx.x * 16 + wave * 4 + grp;   // grid exact: 512*16=8192

    // source-lane tag per rotation k (direction-agnostic)
    int pid[16];
    pid[0]  = nx;
    pid[1]  = ror16<1>(nx);   pid[2]  = ror16<2>(nx);   pid[3]  = ror16<3>(nx);
    pid[4]  = ror16<4>(nx);   pid[5]  = ror16<5>(nx);   pid[6]  = ror16<6>(nx);
    pid[7]  = ror16<7>(nx);   pid[8]  = ror16<8>(nx);   pid[9]  = ror16<9>(nx);
    pid[10] = ror16<10>(nx);  pid[11] = ror16<11>(nx);  pid[12] = ror16<12>(nx);
    pid[13] = ror16<13>(nx);  pid[14] = ror16<14>(nx);  pid[15] = ror16<15>(nx);

    // pre-rotated transition table: trr[k] = T[nx][pid[k]] (NEG_INF if padded)
    float trr[16];
#pragma unroll
    for (int k = 0; k < 16; ++k) {
        const int p = pid[k];
        const bool valid = (nx < NTAG) && (p < NTAG);
        const int ti = valid ? (nx * NTAG + p) : 0;     // clamped (no OOB)
        const float tv = trans[ti];
        trr[k] = valid ? tv : NEG_INF;
    }

    float fv = (nx == 8) ? 0.0f : NEG_INF;   // START=0, else -1e4 (pads too)

    const int nx_ld = (nx < NTAG) ? nx : 0;  // pad lanes load a harmless addr
    const float* fp = feats + b * NTAG + nx_ld;
    uint32_t* bp_out = bpw + b * NTAG + nx_ld;

    float fc[8];
#pragma unroll
    for (int j = 0; j < 8; ++j) fc[j] = fp[j * BT10];
    fp += 8 * BT10;

#define VSTEP(K) { \
        const float r_   = __int_as_float(ror16<K>(fvi)); \
        const float cand = r_ + trr[K]; \
        const bool  wn   = cand > best;        /* strict >: first-in-k wins */ \
        bp   = wn ? pid[K] : bp; \
        best = wn ? cand : best; }

    for (int w = 0; w < SEQ / 8; ++w) {
        float fn[8];
        if (w < SEQ / 8 - 1) {
#pragma unroll
            for (int j = 0; j < 8; ++j) fn[j] = fp[j * BT10];
            fp += 8 * BT10;
        } else {
#pragma unroll
            for (int j = 0; j < 8; ++j) fn[j] = 0.0f;
        }

        uint32_t bacc = 0;
#pragma unroll
        for (int j = 0; j < 8; ++j) {
            const int fvi = __float_as_int(fv);
            float best = fv + trr[0];        // k=0: own lane
            int   bp   = nx;
            VSTEP(1)  VSTEP(2)  VSTEP(3)  VSTEP(4)  VSTEP(5)
            VSTEP(6)  VSTEP(7)  VSTEP(8)  VSTEP(9)  VSTEP(10)
            VSTEP(11) VSTEP(12) VSTEP(13) VSTEP(14) VSTEP(15)
            fv = best + fc[j];               // exact same add as reference
            bacc |= (uint32_t)bp << (4 * j);
        }
        if (nx < NTAG) bp_out[0] = bacc;
        bp_out += BT10;
#pragma unroll
        for (int j = 0; j < 8; ++j) fc[j] = fn[j];
    }
#undef VSTEP

    // terminal: term[p] = fv[p] + T[STOP][p]; gather via shfl (once), exact
    // ascending-p first-max (= jnp.argmax tie semantics).
    {
        const float term = fv + ((nx < NTAG) ? trans[9 * NTAG + nx] : NEG_INF);
        const int base = lane & 48;          // group base lane
        float best = __shfl(term, base + 0, 64);
        int bt = 0;
#pragma unroll
        for (int p = 1; p < NTAG; ++p) {
            const float v = __shfl(term, base + p, 64);
            const bool wn = v > best;
            bt = wn ? p : bt;
            best = wn ? v : best;
        }
        if (nx == 0) { path_score[b] = best; last_tag[b] = bt; }
    }
}

// ---------------------------------------------------------------------------
// Pass A: per (chunk c, batch b) compose the 32 per-step backpointer maps in
// registers. Loads are coalesced (40 contiguous B per thread) and independent
// (no load depends on a tag). Output: packed 40-bit map cmap[c*B + b].
// ---------------------------------------------------------------------------
__global__ __launch_bounds__(256) void crf_chunkmap(
    const uint32_t* __restrict__ bpw, uint64_t* __restrict__ cmap)
{
    const int tid = blockIdx.x * 256 + threadIdx.x;   // 131072 = 16 * 8192
    const int b = tid & (BATCH - 1);
    const int c = tid >> 13;

    uint32_t comp[NTAG];
#pragma unroll
    for (int t = 0; t < NTAG; ++t) comp[t] = t;       // identity

    for (int w = 3; w >= 0; --w) {                    // global word c*4+w
        const uint32_t* wp = bpw + (c * 4 + w) * BT10 + b * NTAG;
        const uint64_t q0 = *(const uint64_t*)(wp + 0);
        const uint64_t q1 = *(const uint64_t*)(wp + 2);
        const uint64_t q2 = *(const uint64_t*)(wp + 4);
        const uint64_t q3 = *(const uint64_t*)(wp + 6);
        const uint64_t q4 = *(const uint64_t*)(wp + 8);
        uint32_t wd[10];
        wd[0] = (uint32_t)q0; wd[1] = (uint32_t)(q0 >> 32);
        wd[2] = (uint32_t)q1; wd[3] = (uint32_t)(q1 >> 32);
        wd[4] = (uint32_t)q2; wd[5] = (uint32_t)(q2 >> 32);
        wd[6] = (uint32_t)q3; wd[7] = (uint32_t)(q3 >> 32);
        wd[8] = (uint32_t)q4; wd[9] = (uint32_t)(q4 >> 32);
#pragma unroll
        for (int t = 7; t >= 0; --t) {
            uint32_t lo = 0;
#pragma unroll
            for (int g = 0; g < 8; ++g) lo |= ((wd[g] >> (4 * t)) & 15u) << (4 * g);
            const uint32_t hi = ((wd[8] >> (4 * t)) & 15u)
                              | (((wd[9] >> (4 * t)) & 15u) << 4);
            const uint64_t m = ((uint64_t)hi << 32) | lo;
#pragma unroll
            for (int q = 0; q < NTAG; ++q)
                comp[q] = (uint32_t)((m >> (comp[q] * 4)) & 15u);
        }
    }
    uint64_t out = 0;
#pragma unroll
    for (int q = 0; q < NTAG; ++q) out |= (uint64_t)comp[q] << (4 * q);
    cmap[tid] = out;                                   // tid = c*8192 + b
}

// ---------------------------------------------------------------------------
// Pass B: resolve chunk-entry tags. 16 independent 8-B loads per thread, then
// a register-space 15-step chain.
// ---------------------------------------------------------------------------
__global__ __launch_bounds__(256) void crf_resolve(
    const uint64_t* __restrict__ cmap, const int* __restrict__ last_tag,
    uint8_t* __restrict__ ebuf)
{
    const int b = blockIdx.x * 256 + threadIdx.x;      // 0..8191
    uint64_t cm[16];
#pragma unroll
    for (int c = 0; c < 16; ++c) cm[c] = cmap[c * BATCH + b];
    uint32_t tag = (uint32_t)last_tag[b];
    ebuf[15 * BATCH + b] = (uint8_t)tag;
#pragma unroll
    for (int c = 15; c >= 1; --c) {
        tag = (uint32_t)((cm[c] >> (tag * 4)) & 15u);
        ebuf[(c - 1) * BATCH + b] = (uint8_t)tag;
    }
}

// ---------------------------------------------------------------------------
// Pass C: emit. Re-walk each chunk with the known entry tag. Loads coalesced
// and independent; per-step word select by tag = 13-op cndmask tree (VALU,
// register-space); stores coalesced over b.
// ---------------------------------------------------------------------------
__global__ __launch_bounds__(256) void crf_emit(
    const uint32_t* __restrict__ bpw, const uint8_t* __restrict__ ebuf,
    float* __restrict__ best_path)
{
    const int tid = blockIdx.x * 256 + threadIdx.x;    // 131072
    const int b = tid & (BATCH - 1);
    const int c = tid >> 13;
    uint32_t tag = ebuf[c * BATCH + b];

    for (int w = 3; w >= 0; --w) {
        const uint32_t* wp = bpw + (c * 4 + w) * BT10 + b * NTAG;
        const uint64_t q0 = *(const uint64_t*)(wp + 0);
        const uint64_t q1 = *(const uint64_t*)(wp + 2);
        const uint64_t q2 = *(const uint64_t*)(wp + 4);
        const uint64_t q3 = *(const uint64_t*)(wp + 6);
        const uint64_t q4 = *(const uint64_t*)(wp + 8);
        uint32_t wd[10];
        wd[0] = (uint32_t)q0; wd[1] = (uint32_t)(q0 >> 32);
        wd[2] = (uint32_t)q1; wd[3] = (uint32_t)(q1 >> 32);
        wd[4] = (uint32_t)q2; wd[5] = (uint32_t)(q2 >> 32);
        wd[6] = (uint32_t)q3; wd[7] = (uint32_t)(q3 >> 32);
        wd[8] = (uint32_t)q4; wd[9] = (uint32_t)(q4 >> 32);
#pragma unroll
        for (int t = 7; t >= 0; --t) {
            best_path[(c * 32 + w * 8 + t) * BATCH + b] = (float)tag;  // tag_t
            const uint32_t s0 = (tag & 1) ? wd[1] : wd[0];
            const uint32_t s2 = (tag & 1) ? wd[3] : wd[2];
            const uint32_t s4 = (tag & 1) ? wd[5] : wd[4];
            const uint32_t s6 = (tag & 1) ? wd[7] : wd[6];
            const uint32_t s8 = (tag & 1) ? wd[9] : wd[8];
            const uint32_t t0 = (tag & 2) ? s2 : s0;
            const uint32_t t4 = (tag & 2) ? s6 : s4;
            const uint32_t u0 = (tag & 4) ? t4 : t0;
            const uint32_t sel = (tag & 8) ? s8 : u0;
            tag = (sel >> (4 * t)) & 15u;                              // tag_{t-1}
        }
    }
}

// ---------------------------------------------------------------------------
// d_ws layout (22.2 MB total, 8-B aligned slots):
//   [0, 20971520)            bpw  : 64 words x 81920 uint32 (nibble bp)
//   [20971520, +32768)       ltag : 8192 int32
//   [21004288, +1048576)     cmap : 16 x 8192 uint64 (packed chunk maps)
//   [22052864, +131072)      ebuf : 16 x 8192 bytes
// ---------------------------------------------------------------------------
extern "C" void kernel_launch(void* const* d_in, const int* in_sizes, int n_in,
                              void* d_out, int out_size, void* d_ws, size_t ws_size,
                              hipStream_t stream)
{
    const float* feats = (const float*)d_in[0];
    const float* trans = (const float*)d_in[1];

    float* out_f      = (float*)d_out;
    float* path_score = out_f;           // [8192]
    float* best_path  = out_f + BATCH;   // [512 * 8192]

    char* ws = (char*)d_ws;
    uint32_t* bpw  = (uint32_t*)ws;
    int*      ltag = (int*)(ws + 20971520);
    uint64_t* cmap = (uint64_t*)(ws + 21004288);
    uint8_t*  ebuf = (uint8_t*)(ws + 22052864);

    crf_fwd<<<512, 256, 0, stream>>>(feats, trans, path_score, ltag, bpw);
    crf_chunkmap<<<512, 256, 0, stream>>>(bpw, cmap);
    crf_resolve<<<32, 256, 0, stream>>>(cmap, ltag, ebuf);
    crf_emit<<<512, 256, 0, stream>>>(bpw, ebuf, best_path);
}

// Round 4
// 321.305 us; speedup vs baseline: 1.3482x; 1.3482x over previous
//
#include <hip/hip_runtime.h>
#include <stdint.h>

#define NTAG    10
#define SEQ     512
#define BATCH   8192
#define NEG_INF -10000.0f
#define BT10    (BATCH * NTAG)   // 81920: per-timestep dword stride
#define ROWF    12               // floats per LDS fv row (48 B)

// ---------------------------------------------------------------------------
// Forward Viterbi. Lane = (batch, next_tag): 10 lanes per batch element,
// 6 groups per wave. fv shared through LDS: per step 1 ds_write_b32 +
// (b128,b128,b64) reads. Same-wave DS ops execute in order on the LDS pipe,
// so no barrier is needed. Compiler ordering/anti-forwarding is enforced by
// laundering the LDS row OFFSET through an empty asm each step (zero instrs):
// the offset becomes opaque -> row[p] may alias any sfv element -> reads
// cannot be forwarded across the write nor hoisted across iterations.
// Global loads (trans/feats) are untouched -> stay register-cached.
// Argmax: ascending-p tournament, strict >, ties keep lower index =
// jnp.argmax semantics. fp32 adds bitwise-identical to the reference.
// ---------------------------------------------------------------------------
__global__ __launch_bounds__(256, 1) void crf_fwd(
    const float* __restrict__ feats, const float* __restrict__ trans,
    float* __restrict__ path_score, int* __restrict__ last_tag,
    uint32_t* __restrict__ bpw)
{
    __shared__ float sfv[4 * 7 * ROWF];   // 4 waves x 7 rows x 12 floats

    const int tid  = threadIdx.x;
    const int wave = tid >> 6;
    const int lane = tid & 63;
    const int g    = lane / 10;           // 0..5 real, 6 = idle lanes
    const int nx   = lane - g * 10;       // 0..9 (idle lanes: 0..3)
    const bool gvalid = (g < 6);

    const int wave_b0 = blockIdx.x * 24 + wave * 6;
    if (wave_b0 >= BATCH) return;         // whole-wave early out
    const int b = wave_b0 + (gvalid ? g : 0);
    const bool active = gvalid && (b < BATCH);
    const int bs = (b < BATCH) ? b : (BATCH - 1);

    const int rowbase = (wave * 7 + g) * ROWF;  // g==6 -> scratch row
    int voff = 0;                                // laundered each step

    // transition row T[nx][p] — register-resident for the whole kernel
    float tr[NTAG];
#pragma unroll
    for (int p = 0; p < NTAG; ++p) tr[p] = trans[nx * NTAG + p];

    float fv = (nx == 8) ? 0.0f : NEG_INF;       // START=0, else -1e4
    sfv[rowbase + nx] = fv;

    const float* fp = feats + bs * NTAG + nx;
    uint32_t* bp_out = bpw + bs * NTAG + nx;

    // software pipeline: 8 feats (one bp-word period) prefetched ahead
    float fc[8];
#pragma unroll
    for (int j = 0; j < 8; ++j) fc[j] = fp[j * BT10];
    fp += 8 * BT10;

    for (int w = 0; w < SEQ / 8; ++w) {
        float fn[8];
        if (w < SEQ / 8 - 1) {
#pragma unroll
            for (int j = 0; j < 8; ++j) fn[j] = fp[j * BT10];
            fp += 8 * BT10;
        } else {
#pragma unroll
            for (int j = 0; j < 8; ++j) fn[j] = 0.0f;
        }

        uint32_t bacc = 0;
#pragma unroll
        for (int j = 0; j < 8; ++j) {
            // launder the LDS offset: opaque value -> no load forwarding,
            // no hoisting across the publish-write; emits zero instructions
            __asm__ __volatile__("" : "+v"(voff));
            const float* row = &sfv[rowbase + voff];

            const float4 A  = *(const float4*)(row);
            const float4 Bv = *(const float4*)(row + 4);
            const float2 Cv = *(const float2*)(row + 8);

            const float c0 = A.x  + tr[0];
            const float c1 = A.y  + tr[1];
            const float c2 = A.z  + tr[2];
            const float c3 = A.w  + tr[3];
            const float c4 = Bv.x + tr[4];
            const float c5 = Bv.y + tr[5];
            const float c6 = Bv.z + tr[6];
            const float c7 = Bv.w + tr[7];
            const float c8 = Cv.x + tr[8];
            const float c9 = Cv.y + tr[9];

            // tournament argmax: strict > takes right, ties keep left
            // (left = smaller index -> first-max = jnp.argmax)
            bool t;
            t = c1 > c0;  float v01 = t ? c1 : c0;  int i01 = t ? 1 : 0;
            t = c3 > c2;  float v23 = t ? c3 : c2;  int i23 = t ? 3 : 2;
            t = c5 > c4;  float v45 = t ? c5 : c4;  int i45 = t ? 5 : 4;
            t = c7 > c6;  float v67 = t ? c7 : c6;  int i67 = t ? 7 : 6;
            t = c9 > c8;  float v89 = t ? c9 : c8;  int i89 = t ? 9 : 8;
            t = v23 > v01; float v03 = t ? v23 : v01; int i03 = t ? i23 : i01;
            t = v67 > v45; float v47 = t ? v67 : v45; int i47 = t ? i67 : i45;
            t = v47 > v03; float v07 = t ? v47 : v03; int i07 = t ? i47 : i03;
            t = v89 > v07; float best = t ? v89 : v07; int bp = t ? i89 : i07;

            fv = best + fc[j];               // exact same add as reference
            bacc |= (uint32_t)bp << (4 * j);

            float* roww = &sfv[rowbase + voff];
            roww[nx] = fv;                   // publish for next step
        }
        if (active) bp_out[0] = bacc;
        bp_out += BT10;
#pragma unroll
        for (int j = 0; j < 8; ++j) fc[j] = fn[j];
    }

    // terminal: term[p] = fv[p] + T[STOP][p]; first-max across the group.
    // Launder once more so the final publish-writes are visible to reads.
    {
        __asm__ __volatile__("" : "+v"(voff));
        const float* row = &sfv[rowbase + voff];
        const float4 A  = *(const float4*)(row);
        const float4 Bv = *(const float4*)(row + 4);
        const float2 Cv = *(const float2*)(row + 8);

        const float c0 = A.x  + trans[90 + 0];
        const float c1 = A.y  + trans[90 + 1];
        const float c2 = A.z  + trans[90 + 2];
        const float c3 = A.w  + trans[90 + 3];
        const float c4 = Bv.x + trans[90 + 4];
        const float c5 = Bv.y + trans[90 + 5];
        const float c6 = Bv.z + trans[90 + 6];
        const float c7 = Bv.w + trans[90 + 7];
        const float c8 = Cv.x + trans[90 + 8];
        const float c9 = Cv.y + trans[90 + 9];

        bool t;
        t = c1 > c0;  float v01 = t ? c1 : c0;  int i01 = t ? 1 : 0;
        t = c3 > c2;  float v23 = t ? c3 : c2;  int i23 = t ? 3 : 2;
        t = c5 > c4;  float v45 = t ? c5 : c4;  int i45 = t ? 5 : 4;
        t = c7 > c6;  float v67 = t ? c7 : c6;  int i67 = t ? 7 : 6;
        t = c9 > c8;  float v89 = t ? c9 : c8;  int i89 = t ? 9 : 8;
        t = v23 > v01; float v03 = t ? v23 : v01; int i03 = t ? i23 : i01;
        t = v67 > v45; float v47 = t ? v67 : v45; int i47 = t ? i67 : i45;
        t = v47 > v03; float v07 = t ? v47 : v03; int i07 = t ? i47 : i03;
        t = v89 > v07; float best = t ? v89 : v07; int bt = t ? i89 : i07;

        if (active && nx == 0) { path_score[b] = best; last_tag[b] = bt; }
    }
}

// ---------------------------------------------------------------------------
// Pass A: per (chunk c, batch b) compose the 32 per-step backpointer maps in
// registers. Loads coalesced (40 contiguous B/thread) and tag-independent.
// ---------------------------------------------------------------------------
__global__ __launch_bounds__(256) void crf_chunkmap(
    const uint32_t* __restrict__ bpw, uint64_t* __restrict__ cmap)
{
    const int tid = blockIdx.x * 256 + threadIdx.x;   // 131072 = 16 * 8192
    const int b = tid & (BATCH - 1);
    const int c = tid >> 13;

    uint32_t comp[NTAG];
#pragma unroll
    for (int t = 0; t < NTAG; ++t) comp[t] = t;       // identity

    for (int w = 3; w >= 0; --w) {                    // global word c*4+w
        const uint32_t* wp = bpw + (c * 4 + w) * BT10 + b * NTAG;
        const uint64_t q0 = *(const uint64_t*)(wp + 0);
        const uint64_t q1 = *(const uint64_t*)(wp + 2);
        const uint64_t q2 = *(const uint64_t*)(wp + 4);
        const uint64_t q3 = *(const uint64_t*)(wp + 6);
        const uint64_t q4 = *(const uint64_t*)(wp + 8);
        uint32_t wd[10];
        wd[0] = (uint32_t)q0; wd[1] = (uint32_t)(q0 >> 32);
        wd[2] = (uint32_t)q1; wd[3] = (uint32_t)(q1 >> 32);
        wd[4] = (uint32_t)q2; wd[5] = (uint32_t)(q2 >> 32);
        wd[6] = (uint32_t)q3; wd[7] = (uint32_t)(q3 >> 32);
        wd[8] = (uint32_t)q4; wd[9] = (uint32_t)(q4 >> 32);
#pragma unroll
        for (int t = 7; t >= 0; --t) {
            uint32_t lo = 0;
#pragma unroll
            for (int gg = 0; gg < 8; ++gg) lo |= ((wd[gg] >> (4 * t)) & 15u) << (4 * gg);
            const uint32_t hi = ((wd[8] >> (4 * t)) & 15u)
                              | (((wd[9] >> (4 * t)) & 15u) << 4);
            const uint64_t m = ((uint64_t)hi << 32) | lo;
#pragma unroll
            for (int q = 0; q < NTAG; ++q)
                comp[q] = (uint32_t)((m >> (comp[q] * 4)) & 15u);
        }
    }
    uint64_t out = 0;
#pragma unroll
    for (int q = 0; q < NTAG; ++q) out |= (uint64_t)comp[q] << (4 * q);
    cmap[tid] = out;                                   // tid = c*8192 + b
}

// ---------------------------------------------------------------------------
// Pass B: resolve chunk-entry tags (16 independent loads + register chain).
// ---------------------------------------------------------------------------
__global__ __launch_bounds__(256) void crf_resolve(
    const uint64_t* __restrict__ cmap, const int* __restrict__ last_tag,
    uint8_t* __restrict__ ebuf)
{
    const int b = blockIdx.x * 256 + threadIdx.x;      // 0..8191
    uint64_t cm[16];
#pragma unroll
    for (int c = 0; c < 16; ++c) cm[c] = cmap[c * BATCH + b];
    uint32_t tag = (uint32_t)last_tag[b];
    ebuf[15 * BATCH + b] = (uint8_t)tag;
#pragma unroll
    for (int c = 15; c >= 1; --c) {
        tag = (uint32_t)((cm[c] >> (tag * 4)) & 15u);
        ebuf[(c - 1) * BATCH + b] = (uint8_t)tag;
    }
}

// ---------------------------------------------------------------------------
// Pass C: emit. Re-walk each chunk with the known entry tag; word select by
// tag = cndmask tree (register-space); stores coalesced over b.
// ---------------------------------------------------------------------------
__global__ __launch_bounds__(256) void crf_emit(
    const uint32_t* __restrict__ bpw, const uint8_t* __restrict__ ebuf,
    float* __restrict__ best_path)
{
    const int tid = blockIdx.x * 256 + threadIdx.x;    // 131072
    const int b = tid & (BATCH - 1);
    const int c = tid >> 13;
    uint32_t tag = ebuf[c * BATCH + b];

    for (int w = 3; w >= 0; --w) {
        const uint32_t* wp = bpw + (c * 4 + w) * BT10 + b * NTAG;
        const uint64_t q0 = *(const uint64_t*)(wp + 0);
        const uint64_t q1 = *(const uint64_t*)(wp + 2);
        const uint64_t q2 = *(const uint64_t*)(wp + 4);
        const uint64_t q3 = *(const uint64_t*)(wp + 6);
        const uint64_t q4 = *(const uint64_t*)(wp + 8);
        uint32_t wd[10];
        wd[0] = (uint32_t)q0; wd[1] = (uint32_t)(q0 >> 32);
        wd[2] = (uint32_t)q1; wd[3] = (uint32_t)(q1 >> 32);
        wd[4] = (uint32_t)q2; wd[5] = (uint32_t)(q2 >> 32);
        wd[6] = (uint32_t)q3; wd[7] = (uint32_t)(q3 >> 32);
        wd[8] = (uint32_t)q4; wd[9] = (uint32_t)(q4 >> 32);
#pragma unroll
        for (int t = 7; t >= 0; --t) {
            best_path[(c * 32 + w * 8 + t) * BATCH + b] = (float)tag;  // tag_t
            const uint32_t s0 = (tag & 1) ? wd[1] : wd[0];
            const uint32_t s2 = (tag & 1) ? wd[3] : wd[2];
            const uint32_t s4 = (tag & 1) ? wd[5] : wd[4];
            const uint32_t s6 = (tag & 1) ? wd[7] : wd[6];
            const uint32_t s8 = (tag & 1) ? wd[9] : wd[8];
            const uint32_t t0 = (tag & 2) ? s2 : s0;
            const uint32_t t4 = (tag & 2) ? s6 : s4;
            const uint32_t u0 = (tag & 4) ? t4 : t0;
            const uint32_t sel = (tag & 8) ? s8 : u0;
            tag = (sel >> (4 * t)) & 15u;                              // tag_{t-1}
        }
    }
}

// ---------------------------------------------------------------------------
// d_ws layout (22.2 MB total):
//   [0, 20971520)            bpw  : 64 words x 81920 uint32 (nibble bp)
//   [20971520, +32768)       ltag : 8192 int32
//   [21004288, +1048576)     cmap : 16 x 8192 uint64 (packed chunk maps)
//   [22052864, +131072)      ebuf : 16 x 8192 bytes
// ---------------------------------------------------------------------------
extern "C" void kernel_launch(void* const* d_in, const int* in_sizes, int n_in,
                              void* d_out, int out_size, void* d_ws, size_t ws_size,
                              hipStream_t stream)
{
    const float* feats = (const float*)d_in[0];
    const float* trans = (const float*)d_in[1];

    float* out_f      = (float*)d_out;
    float* path_score = out_f;           // [8192]
    float* best_path  = out_f + BATCH;   // [512 * 8192]

    char* ws = (char*)d_ws;
    uint32_t* bpw  = (uint32_t*)ws;
    int*      ltag = (int*)(ws + 20971520);
    uint64_t* cmap = (uint64_t*)(ws + 21004288);
    uint8_t*  ebuf = (uint8_t*)(ws + 22052864);

    crf_fwd<<<342, 256, 0, stream>>>(feats, trans, path_score, ltag, bpw);
    crf_chunkmap<<<512, 256, 0, stream>>>(bpw, cmap);
    crf_resolve<<<32, 256, 0, stream>>>(cmap, ltag, ebuf);
    crf_emit<<<512, 256, 0, stream>>>(bpw, ebuf, best_path);
}